// Round 6
// baseline (1753.322 us; speedup 1.0000x reference)
//
#include <hip/hip_runtime.h>
#include <hip/hip_bf16.h>
#include <math.h>

#define KPB 256          // keys per bucket (bucket = key >> 8)
#define BCAP 8192        // entry capacity per bucket (mean ~4092 for E=1.6M -> +64 sigma)

__device__ __forceinline__ float us2f(unsigned short u) {
    return __uint_as_float(((unsigned)u) << 16);
}
__device__ __forceinline__ unsigned short f2bf(float f) {
    unsigned u = __float_as_uint(f);
    u += 0x7FFF + ((u >> 16) & 1);   // RNE
    return (unsigned short)(u >> 16);
}

// ---------------- prep: fold b_gat into fusion bias ----------------
__global__ void prep_kernel(const float* __restrict__ b_gat,
                            const float* __restrict__ W_fus, const float* __restrict__ b_fus,
                            float* __restrict__ bfus2) {
    int t = threadIdx.x;  // 128
    float acc = b_fus[t];
    for (int k = 0; k < 128; k++)
        acc += b_gat[k] * W_fus[t * 256 + 128 + k];
    bfus2[t] = acc;
}

// ---------------- binned CSR build: pass 1 (bin edges) ----------------
// key = col (payload row) for dst-CSR; key = N+row (payload col) for src-CSR
__global__ void bin_kernel(const int* __restrict__ row, const int* __restrict__ col,
                           int* __restrict__ bcnt, int2* __restrict__ stage, int E, int N) {
    int e = blockIdx.x * 256 + threadIdx.x;
    if (e >= E) return;
    int r = row[e], c = col[e];
    int k1 = c, b1 = k1 >> 8;
    int p1 = atomicAdd(&bcnt[b1], 1);
    if (p1 < BCAP) stage[(size_t)b1 * BCAP + p1] = make_int2(k1, r);
    int k2 = N + r, b2 = k2 >> 8;
    int p2 = atomicAdd(&bcnt[b2], 1);
    if (p2 < BCAP) stage[(size_t)b2 * BCAP + p2] = make_int2(k2, c);
}

// ---------------- bucket exclusive scan (single block) ----------------
__global__ void bucket_scan(const int* __restrict__ bcnt, int* __restrict__ bbase, int B) {
    __shared__ int bufA[1024], bufB[1024];
    __shared__ int carry;
    int t = threadIdx.x;
    if (t == 0) carry = 0;
    __syncthreads();
    for (int base = 0; base < B; base += 1024) {
        int i = base + t;
        int v = (i < B) ? min(bcnt[i], BCAP) : 0;
        bufA[t] = v;
        __syncthreads();
        int* s = bufA; int* d = bufB;
        for (int off = 1; off < 1024; off <<= 1) {
            int x = s[t];
            if (t >= off) x += s[t - off];
            d[t] = x;
            __syncthreads();
            int* tmp = s; s = d; d = tmp;
        }
        if (i < B) bbase[i] = carry + s[t] - v;
        __syncthreads();
        if (t == 1023) carry += s[1023];
        __syncthreads();
    }
}

// ---------------- binned CSR build: pass 2 (per-bucket CSR) ----------------
__global__ __launch_bounds__(256) void csr_from_buckets(
    const int2* __restrict__ stage, const int* __restrict__ bcnt,
    const int* __restrict__ bbase, int* __restrict__ row_ptr, int* __restrict__ degs,
    float* __restrict__ dinv, int* __restrict__ adj, int total, int N) {
    __shared__ int hist[256], sA[256], sB[256], cur[256];
    int b = blockIdx.x, t = threadIdx.x;
    int cnt = min(bcnt[b], BCAP);
    int base = bbase[b];
    int k0 = b << 8;
    hist[t] = 0;
    __syncthreads();
    const int2* sp = &stage[(size_t)b * BCAP];
    for (int i = t; i < cnt; i += 256)
        atomicAdd(&hist[sp[i].x - k0], 1);
    __syncthreads();
    // exclusive scan of hist
    int v = hist[t];
    sA[t] = v;
    __syncthreads();
    int* s = sA; int* d = sB;
    for (int off = 1; off < 256; off <<= 1) {
        int x = s[t];
        if (t >= off) x += s[t - off];
        d[t] = x;
        __syncthreads();
        int* tmp = s; s = d; d = tmp;
    }
    int excl = s[t] - v;
    int key = k0 + t;
    if (key < total) {
        row_ptr[key] = base + excl;
        degs[key] = v;
        if (key < N) dinv[key] = v > 0 ? rsqrtf((float)v) : 0.0f;
    }
    cur[t] = base + excl;
    __syncthreads();
    for (int i = t; i < cnt; i += 256) {
        int2 e = sp[i];
        int p = atomicAdd(&cur[e.x - k0], 1);
        adj[p] = e.y;
    }
}

// ------- GEMM: [n,128]@W[128,128]^T (+bias); fp32 out and/or bf16 out -------
__global__ __launch_bounds__(256) void gemm128(
    const float* __restrict__ A, const float* __restrict__ W,
    const float* __restrict__ bias, float* __restrict__ Cf,
    unsigned short* __restrict__ C16, int n) {
    __shared__ float Alds[32 * 132];
    __shared__ float Wlds[32 * 128];
    const int t = threadIdx.x;
    const int row0 = blockIdx.x * 32;

    for (int i = 0; i < 16; i++) {
        int idx = i * 256 + t;
        int r = idx >> 7, k = idx & 127;
        int row = row0 + r;
        Alds[r * 132 + k] = (row < n) ? A[(size_t)row * 128 + k] : 0.f;
    }

    const int rg = t >> 5, cg = t & 31;
    float acc[4][4] = {};

    for (int kt = 0; kt < 4; kt++) {
        __syncthreads();
        for (int i = 0; i < 16; i++) {
            int idx = i * 256 + t;
            int kk = idx >> 7, o = idx & 127;
            Wlds[kk * 128 + o] = W[o * 128 + kt * 32 + kk];
        }
        __syncthreads();

        const float* Ab = &Alds[(rg * 4) * 132 + kt * 32];
        for (int k4 = 0; k4 < 8; k4++) {
            float4 av0 = *(const float4*)&Ab[0 * 132 + k4 * 4];
            float4 av1 = *(const float4*)&Ab[1 * 132 + k4 * 4];
            float4 av2 = *(const float4*)&Ab[2 * 132 + k4 * 4];
            float4 av3 = *(const float4*)&Ab[3 * 132 + k4 * 4];
            float a_[4][4] = {{av0.x, av0.y, av0.z, av0.w},
                              {av1.x, av1.y, av1.z, av1.w},
                              {av2.x, av2.y, av2.z, av2.w},
                              {av3.x, av3.y, av3.z, av3.w}};
#pragma unroll
            for (int kk = 0; kk < 4; kk++) {
                float4 wv = *(const float4*)&Wlds[(k4 * 4 + kk) * 128 + cg * 4];
#pragma unroll
                for (int r = 0; r < 4; r++) {
                    float a = a_[r][kk];
                    acc[r][0] += a * wv.x;
                    acc[r][1] += a * wv.y;
                    acc[r][2] += a * wv.z;
                    acc[r][3] += a * wv.w;
                }
            }
        }
    }
#pragma unroll
    for (int r = 0; r < 4; r++) {
        int row = row0 + rg * 4 + r;
        if (row >= n) continue;
        float4 o;
        o.x = acc[r][0]; o.y = acc[r][1]; o.z = acc[r][2]; o.w = acc[r][3];
        if (bias) {
            o.x += bias[cg * 4 + 0]; o.y += bias[cg * 4 + 1];
            o.z += bias[cg * 4 + 2]; o.w += bias[cg * 4 + 3];
        }
        if (Cf) *(float4*)&Cf[(size_t)row * 128 + cg * 4] = o;
        if (C16) {
            ushort4 q;
            q.x = f2bf(o.x); q.y = f2bf(o.y); q.z = f2bf(o.z); q.w = f2bf(o.w);
            *(ushort4*)&C16[(size_t)row * 128 + cg * 4] = q;
        }
    }
}

// ------- E8 gather (bf16 h): agg[r] = dinv[r] * sum h16[c]*dinv[c] -------
__global__ __launch_bounds__(256) void e8_gather(
    const int* __restrict__ row_ptr, const int* __restrict__ degs,
    const int* __restrict__ adj, const float* __restrict__ dinv,
    const unsigned short* __restrict__ h16, float* __restrict__ agg, int N) {
    int r = blockIdx.x * 4 + (threadIdx.x >> 6);
    int lane = threadIdx.x & 63;
    if (r >= N) return;
    int start = row_ptr[N + r], cnt = degs[N + r];
    float ax = 0.f, ay = 0.f;
    for (int base = 0; base < cnt; base += 64) {
        int m = cnt - base; if (m > 64) m = 64;
        int av = (base + lane < cnt) ? adj[start + base + lane] : 0;
        int j = 0;
        for (; j + 4 <= m; j += 4) {
            int c0 = __shfl(av, j), c1 = __shfl(av, j + 1);
            int c2 = __shfl(av, j + 2), c3 = __shfl(av, j + 3);
            float v0 = dinv[c0], v1 = dinv[c1], v2 = dinv[c2], v3 = dinv[c3];
            ushort2 h0 = *(const ushort2*)&h16[(size_t)c0 * 128 + lane * 2];
            ushort2 h1 = *(const ushort2*)&h16[(size_t)c1 * 128 + lane * 2];
            ushort2 h2 = *(const ushort2*)&h16[(size_t)c2 * 128 + lane * 2];
            ushort2 h3 = *(const ushort2*)&h16[(size_t)c3 * 128 + lane * 2];
            ax += us2f(h0.x) * v0 + us2f(h1.x) * v1 + us2f(h2.x) * v2 + us2f(h3.x) * v3;
            ay += us2f(h0.y) * v0 + us2f(h1.y) * v1 + us2f(h2.y) * v2 + us2f(h3.y) * v3;
        }
        for (; j < m; j++) {
            int c = __shfl(av, j);
            float vc = dinv[c];
            ushort2 hv = *(const ushort2*)&h16[(size_t)c * 128 + lane * 2];
            ax += us2f(hv.x) * vc;
            ay += us2f(hv.y) * vc;
        }
    }
    float dr = dinv[r];
    *(float2*)&agg[(size_t)r * 128 + lane * 2] = make_float2(ax * dr, ay * dr);
}

// ---------------- attention coefficients (bf16 g) ----------------
__global__ void att_kernel(const unsigned short* __restrict__ g16,
                           const float* __restrict__ att_src, const float* __restrict__ att_dst,
                           float* __restrict__ a_src, float* __restrict__ a_dst, int N) {
    int tid = blockIdx.x * 256 + threadIdx.x;
    if (tid >= N * 4) return;
    int n = tid >> 2, hd = tid & 3;
    const unsigned short* gr = &g16[(size_t)n * 128 + hd * 32];
    const float* as = att_src + hd * 32;
    const float* ad = att_dst + hd * 32;
    float s = 0.f, d = 0.f;
    for (int c = 0; c < 32; c += 4) {
        ushort4 gv4 = *(const ushort4*)&gr[c];
        float g0 = us2f(gv4.x), g1 = us2f(gv4.y), g2 = us2f(gv4.z), g3 = us2f(gv4.w);
        float4 sv = *(const float4*)&as[c];
        float4 dv = *(const float4*)&ad[c];
        s += g0 * sv.x + g1 * sv.y + g2 * sv.z + g3 * sv.w;
        d += g0 * dv.x + g1 * dv.y + g2 * dv.z + g3 * dv.w;
    }
    a_src[tid] = s;
    a_dst[tid] = d;
}

// ------- GAT fused: online softmax over dst-CSR (+implicit self-loop), bf16 g -------
__global__ __launch_bounds__(256) void gat_gather(
    const int* __restrict__ row_ptr, const int* __restrict__ degs,
    const int* __restrict__ adj, const float* __restrict__ a_src,
    const float* __restrict__ a_dst, const unsigned short* __restrict__ g16,
    float* __restrict__ xg, int N) {
    int d = blockIdx.x * 4 + (threadIdx.x >> 6);
    int lane = threadIdx.x & 63;
    if (d >= N) return;
    int hd = lane >> 4;
    float ad = a_dst[d * 4 + hd];

    float e = a_src[d * 4 + hd] + ad; e = e > 0.f ? e : 0.2f * e;
    float m0 = e, l = 1.f;
    ushort2 gv0 = *(const ushort2*)&g16[(size_t)d * 128 + lane * 2];
    float accx = us2f(gv0.x), accy = us2f(gv0.y);

    int start = row_ptr[d], cnt = degs[d];
    for (int base = 0; base < cnt; base += 64) {
        int mm = cnt - base; if (mm > 64) mm = 64;
        int av = (base + lane < cnt) ? adj[start + base + lane] : 0;
        int j = 0;
        for (; j + 2 <= mm; j += 2) {
            int s0 = __shfl(av, j), s1 = __shfl(av, j + 1);
            float t0 = a_src[s0 * 4 + hd] + ad; t0 = t0 > 0.f ? t0 : 0.2f * t0;
            float t1 = a_src[s1 * 4 + hd] + ad; t1 = t1 > 0.f ? t1 : 0.2f * t1;
            ushort2 gu0 = *(const ushort2*)&g16[(size_t)s0 * 128 + lane * 2];
            ushort2 gu1 = *(const ushort2*)&g16[(size_t)s1 * 128 + lane * 2];
            float mn = fmaxf(m0, fmaxf(t0, t1));
            float sc = __expf(m0 - mn), w0 = __expf(t0 - mn), w1 = __expf(t1 - mn);
            accx = accx * sc + w0 * us2f(gu0.x) + w1 * us2f(gu1.x);
            accy = accy * sc + w0 * us2f(gu0.y) + w1 * us2f(gu1.y);
            l = l * sc + w0 + w1;
            m0 = mn;
        }
        for (; j < mm; j++) {
            int s = __shfl(av, j);
            float t0 = a_src[s * 4 + hd] + ad; t0 = t0 > 0.f ? t0 : 0.2f * t0;
            ushort2 gu = *(const ushort2*)&g16[(size_t)s * 128 + lane * 2];
            float mn = fmaxf(m0, t0);
            float sc = __expf(m0 - mn), w = __expf(t0 - mn);
            accx = accx * sc + w * us2f(gu.x);
            accy = accy * sc + w * us2f(gu.y);
            l = l * sc + w;
            m0 = mn;
        }
    }
    float inv = 1.f / l;
    *(float2*)&xg[(size_t)d * 128 + lane * 2] = make_float2(accx * inv, accy * inv);
}

// ------- fused fusion (K=256) + residual + LayerNorm + ReLU -------
// z = relu(LN(xe8@Wf[:,:128]^T + xg@Wf[:,128:]^T + bfus2 + h))
__global__ __launch_bounds__(256) void fusion_ln_kernel(
    const float* __restrict__ xe8, const float* __restrict__ xg,
    const float* __restrict__ Wf, const float* __restrict__ bfus2,
    const float* __restrict__ h, const float* __restrict__ gamma,
    const float* __restrict__ beta, float* __restrict__ z, int N) {
    __shared__ float Alds[32 * 132];
    __shared__ float Wlds[32 * 128];
    const int t = threadIdx.x;
    const int row0 = blockIdx.x * 32;
    const int rg = t >> 5, cg = t & 31;
    float acc[4][4] = {};

    for (int phase = 0; phase < 2; phase++) {
        const float* A = phase ? xg : xe8;
        int off = phase * 128;
        __syncthreads();  // previous phase compute done with Alds
        for (int i = 0; i < 16; i++) {
            int idx = i * 256 + t;
            int r = idx >> 7, k = idx & 127;
            int row = row0 + r;
            Alds[r * 132 + k] = (row < N) ? A[(size_t)row * 128 + k] : 0.f;
        }
        for (int kt = 0; kt < 4; kt++) {
            __syncthreads();
            for (int i = 0; i < 16; i++) {
                int idx = i * 256 + t;
                int kk = idx >> 7, o = idx & 127;
                Wlds[kk * 128 + o] = Wf[o * 256 + off + kt * 32 + kk];
            }
            __syncthreads();
            const float* Ab = &Alds[(rg * 4) * 132 + kt * 32];
            for (int k4 = 0; k4 < 8; k4++) {
                float4 av0 = *(const float4*)&Ab[0 * 132 + k4 * 4];
                float4 av1 = *(const float4*)&Ab[1 * 132 + k4 * 4];
                float4 av2 = *(const float4*)&Ab[2 * 132 + k4 * 4];
                float4 av3 = *(const float4*)&Ab[3 * 132 + k4 * 4];
                float a_[4][4] = {{av0.x, av0.y, av0.z, av0.w},
                                  {av1.x, av1.y, av1.z, av1.w},
                                  {av2.x, av2.y, av2.z, av2.w},
                                  {av3.x, av3.y, av3.z, av3.w}};
#pragma unroll
                for (int kk = 0; kk < 4; kk++) {
                    float4 wv = *(const float4*)&Wlds[(k4 * 4 + kk) * 128 + cg * 4];
#pragma unroll
                    for (int r = 0; r < 4; r++) {
                        float a = a_[r][kk];
                        acc[r][0] += a * wv.x;
                        acc[r][1] += a * wv.y;
                        acc[r][2] += a * wv.z;
                        acc[r][3] += a * wv.w;
                    }
                }
            }
        }
    }

    // epilogue: + bfus2 + residual h, then LN+ReLU per row (row = 32 lanes of cg)
    float4 bb = *(const float4*)&bfus2[cg * 4];
    float4 gmv = *(const float4*)&gamma[cg * 4];
    float4 btv = *(const float4*)&beta[cg * 4];
#pragma unroll
    for (int r = 0; r < 4; r++) {
        int row = row0 + rg * 4 + r;
        if (row >= N) continue;
        float4 hv = *(const float4*)&h[(size_t)row * 128 + cg * 4];
        float v0 = acc[r][0] + bb.x + hv.x;
        float v1 = acc[r][1] + bb.y + hv.y;
        float v2 = acc[r][2] + bb.z + hv.z;
        float v3 = acc[r][3] + bb.w + hv.w;
        float s1 = v0 + v1 + v2 + v3;
        float s2 = v0 * v0 + v1 * v1 + v2 * v2 + v3 * v3;
#pragma unroll
        for (int m = 1; m < 32; m <<= 1) {
            s1 += __shfl_xor(s1, m);
            s2 += __shfl_xor(s2, m);
        }
        float mu = s1 * (1.f / 128.f);
        float var = s2 * (1.f / 128.f) - mu * mu;
        float inv = rsqrtf(var + 1e-5f);
        float4 o;
        o.x = (v0 - mu) * inv * gmv.x + btv.x; o.x = o.x > 0.f ? o.x : 0.f;
        o.y = (v1 - mu) * inv * gmv.y + btv.y; o.y = o.y > 0.f ? o.y : 0.f;
        o.z = (v2 - mu) * inv * gmv.z + btv.z; o.z = o.z > 0.f ? o.z : 0.f;
        o.w = (v3 - mu) * inv * gmv.w + btv.w; o.w = o.w > 0.f ? o.w : 0.f;
        *(float4*)&z[(size_t)row * 128 + cg * 4] = o;
    }
}

// --------- readout: r = relu(z@W1^T+b1); out = sigmoid(r@W2+b2) — LDS GEMM ---------
__global__ __launch_bounds__(256) void readout_kernel(
    const float* __restrict__ z, const float* __restrict__ W1, const float* __restrict__ b1,
    const float* __restrict__ W2, const float* __restrict__ b2,
    float* __restrict__ out, int N) {
    __shared__ float zs[32 * 132];
    __shared__ float wlds[64 * 132];
    __shared__ float w2s[64];
    __shared__ float b1s[64];
    const int t = threadIdx.x;
    const int row0 = blockIdx.x * 32;

    for (int i = 0; i < 4; i++) {
        int idx = i * 256 + t;
        int r = idx >> 5, c4 = idx & 31;
        float4 v = make_float4(0.f, 0.f, 0.f, 0.f);
        if (row0 + r < N) v = *(const float4*)&z[(size_t)(row0 + r) * 128 + c4 * 4];
        *(float4*)&zs[r * 132 + c4 * 4] = v;
    }
    for (int i = 0; i < 8; i++) {
        int idx = i * 256 + t;
        int o = idx >> 5, c4 = idx & 31;
        *(float4*)&wlds[o * 132 + c4 * 4] = *(const float4*)&W1[o * 128 + c4 * 4];
    }
    if (t < 64) { w2s[t] = W2[t]; b1s[t] = b1[t]; }
    __syncthreads();

    const int rg = t >> 4;
    const int cg = t & 15;
    float acc[2][4] = {};
    const float* z0 = &zs[(rg * 2) * 132];
    const float* z1 = z0 + 132;
    for (int k4 = 0; k4 < 32; k4++) {
        float4 a0 = *(const float4*)&z0[k4 * 4];
        float4 a1 = *(const float4*)&z1[k4 * 4];
#pragma unroll
        for (int j = 0; j < 4; j++) {
            float4 wv = *(const float4*)&wlds[(cg * 4 + j) * 132 + k4 * 4];
            acc[0][j] += a0.x * wv.x + a0.y * wv.y + a0.z * wv.z + a0.w * wv.w;
            acc[1][j] += a1.x * wv.x + a1.y * wv.y + a1.z * wv.z + a1.w * wv.w;
        }
    }
    float p0 = 0.f, p1 = 0.f;
#pragma unroll
    for (int j = 0; j < 4; j++) {
        int o = cg * 4 + j;
        float r0 = acc[0][j] + b1s[o]; r0 = r0 > 0.f ? r0 : 0.f;
        float r1 = acc[1][j] + b1s[o]; r1 = r1 > 0.f ? r1 : 0.f;
        p0 += r0 * w2s[o]; p1 += r1 * w2s[o];
    }
    for (int off = 8; off > 0; off >>= 1) {
        p0 += __shfl_down(p0, off, 16);
        p1 += __shfl_down(p1, off, 16);
    }
    if (cg == 0) {
        float bb = b2[0];
        int r0i = row0 + rg * 2, r1i = r0i + 1;
        if (r0i < N) out[r0i] = 1.f / (1.f + __expf(-(p0 + bb)));
        if (r1i < N) out[r1i] = 1.f / (1.f + __expf(-(p1 + bb)));
    }
}

extern "C" void kernel_launch(void* const* d_in, const int* in_sizes, int n_in,
                              void* d_out, int out_size, void* d_ws, size_t ws_size,
                              hipStream_t stream) {
    const float* x     = (const float*)d_in[0];
    const int*   ei    = (const int*)d_in[1];
    const float* W_emb = (const float*)d_in[2];
    const float* b_emb = (const float*)d_in[3];
    const float* W_e8  = (const float*)d_in[4];
    const float* W_gat = (const float*)d_in[5];
    const float* att_s = (const float*)d_in[6];
    const float* att_d = (const float*)d_in[7];
    const float* b_gat = (const float*)d_in[8];
    const float* W_fus = (const float*)d_in[9];
    const float* b_fus = (const float*)d_in[10];
    const float* gamma = (const float*)d_in[11];
    const float* beta  = (const float*)d_in[12];
    const float* W_r1  = (const float*)d_in[13];
    const float* b_r1  = (const float*)d_in[14];
    const float* W_r2  = (const float*)d_in[15];
    const float* b_r2  = (const float*)d_in[16];

    const int N = in_sizes[0] / 128;
    const int E = in_sizes[1] / 2;
    const int* rowp = ei;
    const int* colp = ei + E;
    const int total = 2 * N;
    const int B = (total + KPB - 1) / KPB;   // buckets

    const size_t NF = (size_t)N * 128;
    float* ws = (float*)d_ws;
    float* B_h   = ws;            // h fp32 (residual)
    float* B_agg = B_h + NF;      // agg -> xg
    float* B_e8  = B_agg + NF;    // stage || h16 -> x_e8
    float* B_g   = B_e8 + NF;     // stage || g16 -> z
    float* dinv  = B_g + NF;
    float* a_src = dinv + N;
    float* a_dst = a_src + (size_t)4 * N;
    float* bfus2 = a_dst + (size_t)4 * N;
    int* degs    = (int*)(bfus2 + 128);
    int* row_ptr = degs + total;
    int* bcnt    = row_ptr + total;
    int* bbase   = bcnt + 4096;
    int* adj     = bbase + 4096;       // 2E ints

    int2* stage = (int2*)B_e8;                    // B*BCAP entries (51 MB, aliases B_e8+)
    unsigned short* h16 = (unsigned short*)B_e8;  // after stage is dead
    unsigned short* g16 = (unsigned short*)B_g;

    // --- prep + binned CSR build ---
    prep_kernel<<<1, 128, 0, stream>>>(b_gat, W_fus, b_fus, bfus2);
    hipMemsetAsync(bcnt, 0, (size_t)B * 4, stream);
    bin_kernel<<<(E + 255) / 256, 256, 0, stream>>>(rowp, colp, bcnt, stage, E, N);
    bucket_scan<<<1, 1024, 0, stream>>>(bcnt, bbase, B);
    csr_from_buckets<<<B, 256, 0, stream>>>(stage, bcnt, bbase, row_ptr, degs, dinv,
                                            adj, total, N);

    // --- h = x @ W_emb^T + b_emb (fp32 + bf16 side copy) ---
    gemm128<<<(N + 31) / 32, 256, 0, stream>>>(x, W_emb, b_emb, B_h, h16, N);

    // --- E8: gather (bf16 h) + linear ---
    e8_gather<<<(N + 3) / 4, 256, 0, stream>>>(row_ptr, degs, adj, dinv, h16, B_agg, N);
    gemm128<<<(N + 31) / 32, 256, 0, stream>>>(B_agg, W_e8, nullptr, B_e8, nullptr, N);

    // --- GAT: g (bf16 only) + att + fused online-softmax gather ---
    gemm128<<<(N + 31) / 32, 256, 0, stream>>>(B_h, W_gat, nullptr, nullptr, g16, N);
    att_kernel<<<(4 * N + 255) / 256, 256, 0, stream>>>(g16, att_s, att_d, a_src, a_dst, N);
    gat_gather<<<(N + 3) / 4, 256, 0, stream>>>(row_ptr, degs, adj, a_src, a_dst, g16,
                                                B_agg, N);

    // --- fused fusion + residual + LayerNorm + ReLU -> z (B_g) ---
    fusion_ln_kernel<<<(N + 31) / 32, 256, 0, stream>>>(B_e8, B_agg, W_fus, bfus2, B_h,
                                                        gamma, beta, B_g, N);

    // --- readout ---
    readout_kernel<<<(N + 31) / 32, 256, 0, stream>>>(B_g, W_r1, b_r1, W_r2, b_r2,
                                                      (float*)d_out, N);
}

// Round 7
// 1322.499 us; speedup vs baseline: 1.3258x; 1.3258x over previous
//
#include <hip/hip_runtime.h>
#include <hip/hip_bf16.h>
#include <math.h>

#define SCAN_TILE 1024
#define NWIN 8          // fill windows (XCD-affine via blockIdx&7)
#define NCHUNK 128      // edge-list chunks per window

__device__ __forceinline__ float us2f(unsigned short u) {
    return __uint_as_float(((unsigned)u) << 16);
}
__device__ __forceinline__ unsigned short f2bf(float f) {
    unsigned u = __float_as_uint(f);
    u += 0x7FFF + ((u >> 16) & 1);   // RNE
    return (unsigned short)(u >> 16);
}

// ---------------- prep: fold b_gat into fusion bias ----------------
__global__ void prep_kernel(const float* __restrict__ b_gat,
                            const float* __restrict__ W_fus, const float* __restrict__ b_fus,
                            float* __restrict__ bfus2) {
    int t = threadIdx.x;  // 128
    float acc = b_fus[t];
    for (int k = 0; k < 128; k++)
        acc += b_gat[k] * W_fus[t * 256 + 128 + k];
    bfus2[t] = acc;
}

// ---------------- CSR build: count ----------------
__global__ void count_kernel(const int* __restrict__ row, const int* __restrict__ col,
                             int* __restrict__ degs, int E, int N) {
    int e = blockIdx.x * 256 + threadIdx.x;
    if (e >= E) return;
    atomicAdd(&degs[col[e]], 1);       // dst counts (== reference deg)
    atomicAdd(&degs[N + row[e]], 1);   // src counts
}

// ---------------- CSR build: scan ----------------
__global__ void scan_reduce(const int* __restrict__ degs, int* __restrict__ part, int total) {
    int b = blockIdx.x, t = threadIdx.x;  // 256 threads
    int base = b * SCAN_TILE + t * 4;
    int s = 0;
#pragma unroll
    for (int j = 0; j < 4; j++) { int i = base + j; if (i < total) s += degs[i]; }
    __shared__ int red[256];
    red[t] = s; __syncthreads();
    for (int st = 128; st > 0; st >>= 1) {
        if (t < st) red[t] += red[t + st];
        __syncthreads();
    }
    if (t == 0) part[b] = red[0];
}

__global__ void scan_partials(int* __restrict__ part, int P) {
    if (threadIdx.x == 0) {
        int run = 0;
        for (int i = 0; i < P; i++) { int v = part[i]; part[i] = run; run += v; }
    }
}

__global__ void scan_write(const int* __restrict__ degs, const int* __restrict__ part,
                           int* __restrict__ row_ptr, int* __restrict__ cursor,
                           float* __restrict__ dinv, int total, int N) {
    int b = blockIdx.x, t = threadIdx.x;  // 256
    int base = b * SCAN_TILE + t * 4;
    int v[4]; int s = 0;
#pragma unroll
    for (int j = 0; j < 4; j++) { int i = base + j; v[j] = (i < total) ? degs[i] : 0; s += v[j]; }
    __shared__ int bufA[256], bufB[256];
    bufA[t] = s; __syncthreads();
    int* src = bufA; int* dst = bufB;
    for (int off = 1; off < 256; off <<= 1) {
        int x = src[t];
        if (t >= off) x += src[t - off];
        dst[t] = x; __syncthreads();
        int* tp = src; src = dst; dst = tp;
    }
    int excl = src[t] - s;
    int run = part[b] + excl;
#pragma unroll
    for (int j = 0; j < 4; j++) {
        int i = base + j;
        if (i < total) {
            row_ptr[i] = run;
            cursor[i] = run;
            if (i < N) dinv[i] = v[j] > 0 ? rsqrtf((float)v[j]) : 0.0f;
            run += v[j];
        }
    }
}

// ------- CSR build: windowed fill (dense L2-resident adj writes per window) -------
__global__ __launch_bounds__(256) void fill_win(
    const int* __restrict__ row, const int* __restrict__ col,
    int* __restrict__ cursor, int* __restrict__ adj, int E, int N, int win) {
    int b = blockIdx.x;
    int w = b & (NWIN - 1);          // window id (XCD-affine heuristic)
    int chunk = b >> 3;              // log2(NWIN)
    int lo = w * win, hi = lo + win;
    int per = (E + NCHUNK - 1) / NCHUNK;
    int s = chunk * per;
    int e_end = s + per; if (e_end > E) e_end = E;
    for (int i = s + threadIdx.x; i < e_end; i += 256) {
        int r = row[i], c = col[i];
        if (c >= lo && c < hi) {                 // dst-CSR entry
            int p = atomicAdd(&cursor[c], 1);
            adj[p] = r;
        }
        int k2 = N + r;
        if (k2 >= lo && k2 < hi) {               // src-CSR entry
            int p = atomicAdd(&cursor[k2], 1);
            adj[p] = c;
        }
    }
}

// ------- GEMM: [n,128]@W[128,128]^T (+bias); fp32 out and/or bf16 out -------
__global__ __launch_bounds__(256) void gemm128(
    const float* __restrict__ A, const float* __restrict__ W,
    const float* __restrict__ bias, float* __restrict__ Cf,
    unsigned short* __restrict__ C16, int n) {
    __shared__ float Alds[32 * 132];
    __shared__ float Wlds[32 * 128];
    const int t = threadIdx.x;
    const int row0 = blockIdx.x * 32;

    for (int i = 0; i < 16; i++) {
        int idx = i * 256 + t;
        int r = idx >> 7, k = idx & 127;
        int row = row0 + r;
        Alds[r * 132 + k] = (row < n) ? A[(size_t)row * 128 + k] : 0.f;
    }

    const int rg = t >> 5, cg = t & 31;
    float acc[4][4] = {};

    for (int kt = 0; kt < 4; kt++) {
        __syncthreads();
        for (int i = 0; i < 16; i++) {
            int idx = i * 256 + t;
            int kk = idx >> 7, o = idx & 127;
            Wlds[kk * 128 + o] = W[o * 128 + kt * 32 + kk];
        }
        __syncthreads();

        const float* Ab = &Alds[(rg * 4) * 132 + kt * 32];
        for (int k4 = 0; k4 < 8; k4++) {
            float4 av0 = *(const float4*)&Ab[0 * 132 + k4 * 4];
            float4 av1 = *(const float4*)&Ab[1 * 132 + k4 * 4];
            float4 av2 = *(const float4*)&Ab[2 * 132 + k4 * 4];
            float4 av3 = *(const float4*)&Ab[3 * 132 + k4 * 4];
            float a_[4][4] = {{av0.x, av0.y, av0.z, av0.w},
                              {av1.x, av1.y, av1.z, av1.w},
                              {av2.x, av2.y, av2.z, av2.w},
                              {av3.x, av3.y, av3.z, av3.w}};
#pragma unroll
            for (int kk = 0; kk < 4; kk++) {
                float4 wv = *(const float4*)&Wlds[(k4 * 4 + kk) * 128 + cg * 4];
#pragma unroll
                for (int r = 0; r < 4; r++) {
                    float a = a_[r][kk];
                    acc[r][0] += a * wv.x;
                    acc[r][1] += a * wv.y;
                    acc[r][2] += a * wv.z;
                    acc[r][3] += a * wv.w;
                }
            }
        }
    }
#pragma unroll
    for (int r = 0; r < 4; r++) {
        int row = row0 + rg * 4 + r;
        if (row >= n) continue;
        float4 o;
        o.x = acc[r][0]; o.y = acc[r][1]; o.z = acc[r][2]; o.w = acc[r][3];
        if (bias) {
            o.x += bias[cg * 4 + 0]; o.y += bias[cg * 4 + 1];
            o.z += bias[cg * 4 + 2]; o.w += bias[cg * 4 + 3];
        }
        if (Cf) *(float4*)&Cf[(size_t)row * 128 + cg * 4] = o;
        if (C16) {
            ushort4 q;
            q.x = f2bf(o.x); q.y = f2bf(o.y); q.z = f2bf(o.z); q.w = f2bf(o.w);
            *(ushort4*)&C16[(size_t)row * 128 + cg * 4] = q;
        }
    }
}

// ------- E8 gather (bf16 h): agg[r] = dinv[r] * sum h16[c]*dinv[c] -------
__global__ __launch_bounds__(256) void e8_gather(
    const int* __restrict__ row_ptr, const int* __restrict__ degs,
    const int* __restrict__ adj, const float* __restrict__ dinv,
    const unsigned short* __restrict__ h16, float* __restrict__ agg, int N) {
    int r = blockIdx.x * 4 + (threadIdx.x >> 6);
    int lane = threadIdx.x & 63;
    if (r >= N) return;
    int start = row_ptr[N + r], cnt = degs[N + r];
    float ax = 0.f, ay = 0.f;
    for (int base = 0; base < cnt; base += 64) {
        int m = cnt - base; if (m > 64) m = 64;
        int av = (base + lane < cnt) ? adj[start + base + lane] : 0;
        int j = 0;
        for (; j + 4 <= m; j += 4) {
            int c0 = __shfl(av, j), c1 = __shfl(av, j + 1);
            int c2 = __shfl(av, j + 2), c3 = __shfl(av, j + 3);
            float v0 = dinv[c0], v1 = dinv[c1], v2 = dinv[c2], v3 = dinv[c3];
            ushort2 h0 = *(const ushort2*)&h16[(size_t)c0 * 128 + lane * 2];
            ushort2 h1 = *(const ushort2*)&h16[(size_t)c1 * 128 + lane * 2];
            ushort2 h2 = *(const ushort2*)&h16[(size_t)c2 * 128 + lane * 2];
            ushort2 h3 = *(const ushort2*)&h16[(size_t)c3 * 128 + lane * 2];
            ax += us2f(h0.x) * v0 + us2f(h1.x) * v1 + us2f(h2.x) * v2 + us2f(h3.x) * v3;
            ay += us2f(h0.y) * v0 + us2f(h1.y) * v1 + us2f(h2.y) * v2 + us2f(h3.y) * v3;
        }
        for (; j < m; j++) {
            int c = __shfl(av, j);
            float vc = dinv[c];
            ushort2 hv = *(const ushort2*)&h16[(size_t)c * 128 + lane * 2];
            ax += us2f(hv.x) * vc;
            ay += us2f(hv.y) * vc;
        }
    }
    float dr = dinv[r];
    *(float2*)&agg[(size_t)r * 128 + lane * 2] = make_float2(ax * dr, ay * dr);
}

// ---------------- attention coefficients (bf16 g) ----------------
__global__ void att_kernel(const unsigned short* __restrict__ g16,
                           const float* __restrict__ att_src, const float* __restrict__ att_dst,
                           float* __restrict__ a_src, float* __restrict__ a_dst, int N) {
    int tid = blockIdx.x * 256 + threadIdx.x;
    if (tid >= N * 4) return;
    int n = tid >> 2, hd = tid & 3;
    const unsigned short* gr = &g16[(size_t)n * 128 + hd * 32];
    const float* as = att_src + hd * 32;
    const float* ad = att_dst + hd * 32;
    float s = 0.f, d = 0.f;
    for (int c = 0; c < 32; c += 4) {
        ushort4 gv4 = *(const ushort4*)&gr[c];
        float g0 = us2f(gv4.x), g1 = us2f(gv4.y), g2 = us2f(gv4.z), g3 = us2f(gv4.w);
        float4 sv = *(const float4*)&as[c];
        float4 dv = *(const float4*)&ad[c];
        s += g0 * sv.x + g1 * sv.y + g2 * sv.z + g3 * sv.w;
        d += g0 * dv.x + g1 * dv.y + g2 * dv.z + g3 * dv.w;
    }
    a_src[tid] = s;
    a_dst[tid] = d;
}

// ------- GAT fused: online softmax over dst-CSR (+implicit self-loop), bf16 g -------
__global__ __launch_bounds__(256) void gat_gather(
    const int* __restrict__ row_ptr, const int* __restrict__ degs,
    const int* __restrict__ adj, const float* __restrict__ a_src,
    const float* __restrict__ a_dst, const unsigned short* __restrict__ g16,
    float* __restrict__ xg, int N) {
    int d = blockIdx.x * 4 + (threadIdx.x >> 6);
    int lane = threadIdx.x & 63;
    if (d >= N) return;
    int hd = lane >> 4;
    float ad = a_dst[d * 4 + hd];

    float e = a_src[d * 4 + hd] + ad; e = e > 0.f ? e : 0.2f * e;
    float m0 = e, l = 1.f;
    ushort2 gv0 = *(const ushort2*)&g16[(size_t)d * 128 + lane * 2];
    float accx = us2f(gv0.x), accy = us2f(gv0.y);

    int start = row_ptr[d], cnt = degs[d];
    for (int base = 0; base < cnt; base += 64) {
        int mm = cnt - base; if (mm > 64) mm = 64;
        int av = (base + lane < cnt) ? adj[start + base + lane] : 0;
        int j = 0;
        for (; j + 2 <= mm; j += 2) {
            int s0 = __shfl(av, j), s1 = __shfl(av, j + 1);
            float t0 = a_src[s0 * 4 + hd] + ad; t0 = t0 > 0.f ? t0 : 0.2f * t0;
            float t1 = a_src[s1 * 4 + hd] + ad; t1 = t1 > 0.f ? t1 : 0.2f * t1;
            ushort2 gu0 = *(const ushort2*)&g16[(size_t)s0 * 128 + lane * 2];
            ushort2 gu1 = *(const ushort2*)&g16[(size_t)s1 * 128 + lane * 2];
            float mn = fmaxf(m0, fmaxf(t0, t1));
            float sc = __expf(m0 - mn), w0 = __expf(t0 - mn), w1 = __expf(t1 - mn);
            accx = accx * sc + w0 * us2f(gu0.x) + w1 * us2f(gu1.x);
            accy = accy * sc + w0 * us2f(gu0.y) + w1 * us2f(gu1.y);
            l = l * sc + w0 + w1;
            m0 = mn;
        }
        for (; j < mm; j++) {
            int s = __shfl(av, j);
            float t0 = a_src[s * 4 + hd] + ad; t0 = t0 > 0.f ? t0 : 0.2f * t0;
            ushort2 gu = *(const ushort2*)&g16[(size_t)s * 128 + lane * 2];
            float mn = fmaxf(m0, t0);
            float sc = __expf(m0 - mn), w = __expf(t0 - mn);
            accx = accx * sc + w * us2f(gu.x);
            accy = accy * sc + w * us2f(gu.y);
            l = l * sc + w;
            m0 = mn;
        }
    }
    float inv = 1.f / l;
    *(float2*)&xg[(size_t)d * 128 + lane * 2] = make_float2(accx * inv, accy * inv);
}

// ------- fused fusion (K=256) + residual + LayerNorm + ReLU -------
__global__ __launch_bounds__(256) void fusion_ln_kernel(
    const float* __restrict__ xe8, const float* __restrict__ xg,
    const float* __restrict__ Wf, const float* __restrict__ bfus2,
    const float* __restrict__ h, const float* __restrict__ gamma,
    const float* __restrict__ beta, float* __restrict__ z, int N) {
    __shared__ float Alds[32 * 132];
    __shared__ float Wlds[32 * 128];
    const int t = threadIdx.x;
    const int row0 = blockIdx.x * 32;
    const int rg = t >> 5, cg = t & 31;
    float acc[4][4] = {};

    for (int phase = 0; phase < 2; phase++) {
        const float* A = phase ? xg : xe8;
        int off = phase * 128;
        __syncthreads();
        for (int i = 0; i < 16; i++) {
            int idx = i * 256 + t;
            int r = idx >> 7, k = idx & 127;
            int row = row0 + r;
            Alds[r * 132 + k] = (row < N) ? A[(size_t)row * 128 + k] : 0.f;
        }
        for (int kt = 0; kt < 4; kt++) {
            __syncthreads();
            for (int i = 0; i < 16; i++) {
                int idx = i * 256 + t;
                int kk = idx >> 7, o = idx & 127;
                Wlds[kk * 128 + o] = Wf[o * 256 + off + kt * 32 + kk];
            }
            __syncthreads();
            const float* Ab = &Alds[(rg * 4) * 132 + kt * 32];
            for (int k4 = 0; k4 < 8; k4++) {
                float4 av0 = *(const float4*)&Ab[0 * 132 + k4 * 4];
                float4 av1 = *(const float4*)&Ab[1 * 132 + k4 * 4];
                float4 av2 = *(const float4*)&Ab[2 * 132 + k4 * 4];
                float4 av3 = *(const float4*)&Ab[3 * 132 + k4 * 4];
                float a_[4][4] = {{av0.x, av0.y, av0.z, av0.w},
                                  {av1.x, av1.y, av1.z, av1.w},
                                  {av2.x, av2.y, av2.z, av2.w},
                                  {av3.x, av3.y, av3.z, av3.w}};
#pragma unroll
                for (int kk = 0; kk < 4; kk++) {
                    float4 wv = *(const float4*)&Wlds[(k4 * 4 + kk) * 128 + cg * 4];
#pragma unroll
                    for (int r = 0; r < 4; r++) {
                        float a = a_[r][kk];
                        acc[r][0] += a * wv.x;
                        acc[r][1] += a * wv.y;
                        acc[r][2] += a * wv.z;
                        acc[r][3] += a * wv.w;
                    }
                }
            }
        }
    }

    float4 bb = *(const float4*)&bfus2[cg * 4];
    float4 gmv = *(const float4*)&gamma[cg * 4];
    float4 btv = *(const float4*)&beta[cg * 4];
#pragma unroll
    for (int r = 0; r < 4; r++) {
        int row = row0 + rg * 4 + r;
        if (row >= N) continue;
        float4 hv = *(const float4*)&h[(size_t)row * 128 + cg * 4];
        float v0 = acc[r][0] + bb.x + hv.x;
        float v1 = acc[r][1] + bb.y + hv.y;
        float v2 = acc[r][2] + bb.z + hv.z;
        float v3 = acc[r][3] + bb.w + hv.w;
        float s1 = v0 + v1 + v2 + v3;
        float s2 = v0 * v0 + v1 * v1 + v2 * v2 + v3 * v3;
#pragma unroll
        for (int m = 1; m < 32; m <<= 1) {
            s1 += __shfl_xor(s1, m);
            s2 += __shfl_xor(s2, m);
        }
        float mu = s1 * (1.f / 128.f);
        float var = s2 * (1.f / 128.f) - mu * mu;
        float inv = rsqrtf(var + 1e-5f);
        float4 o;
        o.x = (v0 - mu) * inv * gmv.x + btv.x; o.x = o.x > 0.f ? o.x : 0.f;
        o.y = (v1 - mu) * inv * gmv.y + btv.y; o.y = o.y > 0.f ? o.y : 0.f;
        o.z = (v2 - mu) * inv * gmv.z + btv.z; o.z = o.z > 0.f ? o.z : 0.f;
        o.w = (v3 - mu) * inv * gmv.w + btv.w; o.w = o.w > 0.f ? o.w : 0.f;
        *(float4*)&z[(size_t)row * 128 + cg * 4] = o;
    }
}

// --------- readout: r = relu(z@W1^T+b1); out = sigmoid(r@W2+b2) — LDS GEMM ---------
__global__ __launch_bounds__(256) void readout_kernel(
    const float* __restrict__ z, const float* __restrict__ W1, const float* __restrict__ b1,
    const float* __restrict__ W2, const float* __restrict__ b2,
    float* __restrict__ out, int N) {
    __shared__ float zs[32 * 132];
    __shared__ float wlds[64 * 132];
    __shared__ float w2s[64];
    __shared__ float b1s[64];
    const int t = threadIdx.x;
    const int row0 = blockIdx.x * 32;

    for (int i = 0; i < 4; i++) {
        int idx = i * 256 + t;
        int r = idx >> 5, c4 = idx & 31;
        float4 v = make_float4(0.f, 0.f, 0.f, 0.f);
        if (row0 + r < N) v = *(const float4*)&z[(size_t)(row0 + r) * 128 + c4 * 4];
        *(float4*)&zs[r * 132 + c4 * 4] = v;
    }
    for (int i = 0; i < 8; i++) {
        int idx = i * 256 + t;
        int o = idx >> 5, c4 = idx & 31;
        *(float4*)&wlds[o * 132 + c4 * 4] = *(const float4*)&W1[o * 128 + c4 * 4];
    }
    if (t < 64) { w2s[t] = W2[t]; b1s[t] = b1[t]; }
    __syncthreads();

    const int rg = t >> 4;
    const int cg = t & 15;
    float acc[2][4] = {};
    const float* z0 = &zs[(rg * 2) * 132];
    const float* z1 = z0 + 132;
    for (int k4 = 0; k4 < 32; k4++) {
        float4 a0 = *(const float4*)&z0[k4 * 4];
        float4 a1 = *(const float4*)&z1[k4 * 4];
#pragma unroll
        for (int j = 0; j < 4; j++) {
            float4 wv = *(const float4*)&wlds[(cg * 4 + j) * 132 + k4 * 4];
            acc[0][j] += a0.x * wv.x + a0.y * wv.y + a0.z * wv.z + a0.w * wv.w;
            acc[1][j] += a1.x * wv.x + a1.y * wv.y + a1.z * wv.z + a1.w * wv.w;
        }
    }
    float p0 = 0.f, p1 = 0.f;
#pragma unroll
    for (int j = 0; j < 4; j++) {
        int o = cg * 4 + j;
        float r0 = acc[0][j] + b1s[o]; r0 = r0 > 0.f ? r0 : 0.f;
        float r1 = acc[1][j] + b1s[o]; r1 = r1 > 0.f ? r1 : 0.f;
        p0 += r0 * w2s[o]; p1 += r1 * w2s[o];
    }
    for (int off = 8; off > 0; off >>= 1) {
        p0 += __shfl_down(p0, off, 16);
        p1 += __shfl_down(p1, off, 16);
    }
    if (cg == 0) {
        float bb = b2[0];
        int r0i = row0 + rg * 2, r1i = r0i + 1;
        if (r0i < N) out[r0i] = 1.f / (1.f + __expf(-(p0 + bb)));
        if (r1i < N) out[r1i] = 1.f / (1.f + __expf(-(p1 + bb)));
    }
}

extern "C" void kernel_launch(void* const* d_in, const int* in_sizes, int n_in,
                              void* d_out, int out_size, void* d_ws, size_t ws_size,
                              hipStream_t stream) {
    const float* x     = (const float*)d_in[0];
    const int*   ei    = (const int*)d_in[1];
    const float* W_emb = (const float*)d_in[2];
    const float* b_emb = (const float*)d_in[3];
    const float* W_e8  = (const float*)d_in[4];
    const float* W_gat = (const float*)d_in[5];
    const float* att_s = (const float*)d_in[6];
    const float* att_d = (const float*)d_in[7];
    const float* b_gat = (const float*)d_in[8];
    const float* W_fus = (const float*)d_in[9];
    const float* b_fus = (const float*)d_in[10];
    const float* gamma = (const float*)d_in[11];
    const float* beta  = (const float*)d_in[12];
    const float* W_r1  = (const float*)d_in[13];
    const float* b_r1  = (const float*)d_in[14];
    const float* W_r2  = (const float*)d_in[15];
    const float* b_r2  = (const float*)d_in[16];

    const int N = in_sizes[0] / 128;
    const int E = in_sizes[1] / 2;
    const int* rowp = ei;
    const int* colp = ei + E;
    const int total = 2 * N;
    const int P = (total + SCAN_TILE - 1) / SCAN_TILE;
    const int win = (total + NWIN - 1) / NWIN;

    const size_t NF = (size_t)N * 128;
    float* ws = (float*)d_ws;
    float* B_h   = ws;            // h fp32 (residual)
    float* B_agg = B_h + NF;      // e8 agg -> xg
    float* B_e8  = B_agg + NF;    // h16 -> x_e8
    float* B_g   = B_e8 + NF;     // g16 -> z
    float* dinv  = B_g + NF;
    float* a_src = dinv + N;
    float* a_dst = a_src + (size_t)4 * N;
    float* bfus2 = a_dst + (size_t)4 * N;
    int* degs    = (int*)(bfus2 + 128);
    int* row_ptr = degs + total;
    int* cursor  = row_ptr + total;
    int* part    = cursor + total;
    int* adj     = part + 1024;       // 2E ints

    unsigned short* h16 = (unsigned short*)B_e8;  // dead once x_e8 written
    unsigned short* g16 = (unsigned short*)B_g;   // dead once z written

    // --- prep + CSR build (count -> scan -> windowed fill) ---
    prep_kernel<<<1, 128, 0, stream>>>(b_gat, W_fus, b_fus, bfus2);
    hipMemsetAsync(degs, 0, (size_t)total * 4, stream);
    count_kernel<<<(E + 255) / 256, 256, 0, stream>>>(rowp, colp, degs, E, N);
    scan_reduce<<<P, 256, 0, stream>>>(degs, part, total);
    scan_partials<<<1, 64, 0, stream>>>(part, P);
    scan_write<<<P, 256, 0, stream>>>(degs, part, row_ptr, cursor, dinv, total, N);
    fill_win<<<NWIN * NCHUNK, 256, 0, stream>>>(rowp, colp, cursor, adj, E, N, win);

    // --- h = x @ W_emb^T + b_emb (fp32 + bf16 side copy) ---
    gemm128<<<(N + 31) / 32, 256, 0, stream>>>(x, W_emb, b_emb, B_h, h16, N);

    // --- E8: gather (bf16 h) + linear ---
    e8_gather<<<(N + 3) / 4, 256, 0, stream>>>(row_ptr, degs, adj, dinv, h16, B_agg, N);
    gemm128<<<(N + 31) / 32, 256, 0, stream>>>(B_agg, W_e8, nullptr, B_e8, nullptr, N);

    // --- GAT: g (bf16) + att + fused online-softmax gather ---
    gemm128<<<(N + 31) / 32, 256, 0, stream>>>(B_h, W_gat, nullptr, nullptr, g16, N);
    att_kernel<<<(4 * N + 255) / 256, 256, 0, stream>>>(g16, att_s, att_d, a_src, a_dst, N);
    gat_gather<<<(N + 3) / 4, 256, 0, stream>>>(row_ptr, degs, adj, a_src, a_dst, g16,
                                                B_agg, N);

    // --- fused fusion + residual + LayerNorm + ReLU -> z (B_g) ---
    fusion_ln_kernel<<<(N + 31) / 32, 256, 0, stream>>>(B_e8, B_agg, W_fus, bfus2, B_h,
                                                        gamma, beta, B_g, N);

    // --- readout ---
    readout_kernel<<<(N + 31) / 32, 256, 0, stream>>>(B_g, W_r1, b_r1, W_r2, b_r2,
                                                      (float*)d_out, N);
}

// Round 8
// 768.183 us; speedup vs baseline: 2.2824x; 1.7216x over previous
//
#include <hip/hip_runtime.h>
#include <hip/hip_bf16.h>
#include <math.h>

#define SCAN_TILE 1024
#define NWIN 8          // fill windows (XCD-affine via blockIdx&7)
#define NCHUNK 128      // edge-list chunks per window

typedef __attribute__((ext_vector_type(8))) short bf16x8;
typedef __attribute__((ext_vector_type(4))) float f32x4;

__device__ __forceinline__ float us2f(unsigned short u) {
    return __uint_as_float(((unsigned)u) << 16);
}
__device__ __forceinline__ unsigned short f2bf(float f) {
    unsigned u = __float_as_uint(f);
    u += 0x7FFF + ((u >> 16) & 1);   // RNE
    return (unsigned short)(u >> 16);
}

// ---------------- prep: fold b_gat into fusion bias ----------------
__global__ void prep_kernel(const float* __restrict__ b_gat,
                            const float* __restrict__ W_fus, const float* __restrict__ b_fus,
                            float* __restrict__ bfus2) {
    int t = threadIdx.x;  // 128
    float acc = b_fus[t];
    for (int k = 0; k < 128; k++)
        acc += b_gat[k] * W_fus[t * 256 + 128 + k];
    bfus2[t] = acc;
}

// ---------------- convert weights to bf16 arena ----------------
// layout: We16[16384] | W8_16[16384] | Wg16[16384] | Wf16[32768]
__global__ void convert_w(const float* __restrict__ We, const float* __restrict__ W8,
                          const float* __restrict__ Wg, const float* __restrict__ Wf,
                          unsigned short* __restrict__ W16) {
    int i = blockIdx.x * 256 + threadIdx.x;
    if (i >= 81920) return;
    float v;
    if (i < 16384) v = We[i];
    else if (i < 32768) v = W8[i - 16384];
    else if (i < 49152) v = Wg[i - 32768];
    else v = Wf[i - 49152];
    W16[i] = f2bf(v);
}

// ---------------- CSR build: count ----------------
__global__ void count_kernel(const int* __restrict__ row, const int* __restrict__ col,
                             int* __restrict__ degs, int E, int N) {
    int e = blockIdx.x * 256 + threadIdx.x;
    if (e >= E) return;
    atomicAdd(&degs[col[e]], 1);       // dst counts (== reference deg)
    atomicAdd(&degs[N + row[e]], 1);   // src counts
}

// ---------------- CSR build: scan ----------------
__global__ void scan_reduce(const int* __restrict__ degs, int* __restrict__ part, int total) {
    int b = blockIdx.x, t = threadIdx.x;  // 256 threads
    int base = b * SCAN_TILE + t * 4;
    int s = 0;
#pragma unroll
    for (int j = 0; j < 4; j++) { int i = base + j; if (i < total) s += degs[i]; }
    __shared__ int red[256];
    red[t] = s; __syncthreads();
    for (int st = 128; st > 0; st >>= 1) {
        if (t < st) red[t] += red[t + st];
        __syncthreads();
    }
    if (t == 0) part[b] = red[0];
}

__global__ void scan_partials(int* __restrict__ part, int P) {
    if (threadIdx.x == 0) {
        int run = 0;
        for (int i = 0; i < P; i++) { int v = part[i]; part[i] = run; run += v; }
    }
}

__global__ void scan_write(const int* __restrict__ degs, const int* __restrict__ part,
                           int* __restrict__ row_ptr, int* __restrict__ cursor,
                           float* __restrict__ dinv, int total, int N) {
    int b = blockIdx.x, t = threadIdx.x;  // 256
    int base = b * SCAN_TILE + t * 4;
    int v[4]; int s = 0;
#pragma unroll
    for (int j = 0; j < 4; j++) { int i = base + j; v[j] = (i < total) ? degs[i] : 0; s += v[j]; }
    __shared__ int bufA[256], bufB[256];
    bufA[t] = s; __syncthreads();
    int* src = bufA; int* dst = bufB;
    for (int off = 1; off < 256; off <<= 1) {
        int x = src[t];
        if (t >= off) x += src[t - off];
        dst[t] = x; __syncthreads();
        int* tp = src; src = dst; dst = tp;
    }
    int excl = src[t] - s;
    int run = part[b] + excl;
#pragma unroll
    for (int j = 0; j < 4; j++) {
        int i = base + j;
        if (i < total) {
            row_ptr[i] = run;
            cursor[i] = run;
            if (i < N) dinv[i] = v[j] > 0 ? rsqrtf((float)v[j]) : 0.0f;
            run += v[j];
        }
    }
}

// ------- CSR build: windowed fill (dense L2-resident adj writes per window) -------
__global__ __launch_bounds__(256) void fill_win(
    const int* __restrict__ row, const int* __restrict__ col,
    int* __restrict__ cursor, int* __restrict__ adj, int E, int N, int win) {
    int b = blockIdx.x;
    int w = b & (NWIN - 1);
    int chunk = b >> 3;
    int lo = w * win, hi = lo + win;
    int per = (E + NCHUNK - 1) / NCHUNK;
    int s = chunk * per;
    int e_end = s + per; if (e_end > E) e_end = E;
    for (int i = s + threadIdx.x; i < e_end; i += 256) {
        int r = row[i], c = col[i];
        if (c >= lo && c < hi) {
            int p = atomicAdd(&cursor[c], 1);
            adj[p] = r;
        }
        int k2 = N + r;
        if (k2 >= lo && k2 < hi) {
            int p = atomicAdd(&cursor[k2], 1);
            adj[p] = c;
        }
    }
}

// ------- MFMA GEMM: C[n,128] = A[n,128] @ W16[128,128]^T (+bias) -------
// 128 rows x 128 cols per block (4 waves, wave = 32 rows). No LDS.
template <bool A_FP32, bool HAS_BIAS, bool OUT_F32, bool OUT_BF16>
__global__ __launch_bounds__(256) void gemm_mfma(
    const void* __restrict__ A_, const unsigned short* __restrict__ W16,
    const float* __restrict__ bias, float* __restrict__ Cf,
    unsigned short* __restrict__ C16, int n) {
    const int t = threadIdx.x;
    const int wave = t >> 6, lane = t & 63;
    const int quad = lane >> 4, ln = lane & 15;
    const int row0 = blockIdx.x * 128 + wave * 32;
    const int kq = quad * 8;

    f32x4 zero = {0.f, 0.f, 0.f, 0.f};
    f32x4 acc[2][8];
#pragma unroll
    for (int i = 0; i < 2; i++)
#pragma unroll
        for (int j = 0; j < 8; j++) acc[i][j] = zero;

#pragma unroll
    for (int ks = 0; ks < 4; ks++) {
        bf16x8 a[2];
#pragma unroll
        for (int mt = 0; mt < 2; mt++) {
            int row = row0 + mt * 16 + ln;
            if (row >= n) row = n - 1;   // clamp (stores guarded)
            if (A_FP32) {
                const float* ap = (const float*)A_ + (size_t)row * 128 + ks * 32 + kq;
                float4 f0 = *(const float4*)ap;
                float4 f1 = *(const float4*)(ap + 4);
                bf16x8 v;
                v[0] = (short)f2bf(f0.x); v[1] = (short)f2bf(f0.y);
                v[2] = (short)f2bf(f0.z); v[3] = (short)f2bf(f0.w);
                v[4] = (short)f2bf(f1.x); v[5] = (short)f2bf(f1.y);
                v[6] = (short)f2bf(f1.z); v[7] = (short)f2bf(f1.w);
                a[mt] = v;
            } else {
                a[mt] = *(const bf16x8*)((const unsigned short*)A_ +
                                         (size_t)row * 128 + ks * 32 + kq);
            }
        }
#pragma unroll
        for (int nt = 0; nt < 8; nt++) {
            bf16x8 b = *(const bf16x8*)(W16 + (size_t)(nt * 16 + ln) * 128 + ks * 32 + kq);
            acc[0][nt] = __builtin_amdgcn_mfma_f32_16x16x32_bf16(a[0], b, acc[0][nt], 0, 0, 0);
            acc[1][nt] = __builtin_amdgcn_mfma_f32_16x16x32_bf16(a[1], b, acc[1][nt], 0, 0, 0);
        }
    }

    float bv[8];
    if (HAS_BIAS) {
#pragma unroll
        for (int nt = 0; nt < 8; nt++) bv[nt] = bias[nt * 16 + ln];
    }
#pragma unroll
    for (int mt = 0; mt < 2; mt++) {
        int rbase = row0 + mt * 16 + quad * 4;
#pragma unroll
        for (int reg = 0; reg < 4; reg++) {
            int row = rbase + reg;
            if (row >= n) continue;
#pragma unroll
            for (int nt = 0; nt < 8; nt++) {
                float v = acc[mt][nt][reg];
                if (HAS_BIAS) v += bv[nt];
                int col = nt * 16 + ln;
                if (OUT_F32) Cf[(size_t)row * 128 + col] = v;
                if (OUT_BF16) C16[(size_t)row * 128 + col] = f2bf(v);
            }
        }
    }
}

// ------- MFMA fusion (K=256) + residual + LayerNorm + ReLU -> z fp32 -------
__global__ __launch_bounds__(256) void fusion_ln_mfma(
    const unsigned short* __restrict__ xe816, const unsigned short* __restrict__ xg16,
    const unsigned short* __restrict__ Wf16,   // [128][256] row-major bf16
    const float* __restrict__ bfus2, const float* __restrict__ h,
    const float* __restrict__ gamma, const float* __restrict__ beta,
    float* __restrict__ z, int n) {
    const int t = threadIdx.x;
    const int wave = t >> 6, lane = t & 63;
    const int quad = lane >> 4, ln = lane & 15;
    const int row0 = blockIdx.x * 128 + wave * 32;
    const int kq = quad * 8;

    f32x4 zero = {0.f, 0.f, 0.f, 0.f};
    f32x4 acc[2][8];
#pragma unroll
    for (int i = 0; i < 2; i++)
#pragma unroll
        for (int j = 0; j < 8; j++) acc[i][j] = zero;

    for (int half = 0; half < 2; half++) {
        const unsigned short* A = half ? xg16 : xe816;
#pragma unroll
        for (int ks = 0; ks < 4; ks++) {
            bf16x8 a[2];
#pragma unroll
            for (int mt = 0; mt < 2; mt++) {
                int row = row0 + mt * 16 + ln;
                if (row >= n) row = n - 1;
                a[mt] = *(const bf16x8*)(A + (size_t)row * 128 + ks * 32 + kq);
            }
#pragma unroll
            for (int nt = 0; nt < 8; nt++) {
                bf16x8 b = *(const bf16x8*)(Wf16 + (size_t)(nt * 16 + ln) * 256 +
                                            half * 128 + ks * 32 + kq);
                acc[0][nt] = __builtin_amdgcn_mfma_f32_16x16x32_bf16(a[0], b, acc[0][nt], 0, 0, 0);
                acc[1][nt] = __builtin_amdgcn_mfma_f32_16x16x32_bf16(a[1], b, acc[1][nt], 0, 0, 0);
            }
        }
    }

    float bv[8], gm[8], bt[8];
#pragma unroll
    for (int nt = 0; nt < 8; nt++) {
        int c = nt * 16 + ln;
        bv[nt] = bfus2[c]; gm[nt] = gamma[c]; bt[nt] = beta[c];
    }
#pragma unroll
    for (int mt = 0; mt < 2; mt++) {
#pragma unroll
        for (int reg = 0; reg < 4; reg++) {
            int row = row0 + mt * 16 + quad * 4 + reg;   // uniform across the quad
            if (row >= n) continue;
            float v[8];
            float s1 = 0.f, s2 = 0.f;
#pragma unroll
            for (int nt = 0; nt < 8; nt++) {
                float x = acc[mt][nt][reg] + bv[nt] + h[(size_t)row * 128 + nt * 16 + ln];
                v[nt] = x; s1 += x; s2 += x * x;
            }
#pragma unroll
            for (int m = 1; m < 16; m <<= 1) {
                s1 += __shfl_xor(s1, m);
                s2 += __shfl_xor(s2, m);
            }
            float mu = s1 * (1.f / 128.f);
            float var = s2 * (1.f / 128.f) - mu * mu;
            float inv = rsqrtf(var + 1e-5f);
#pragma unroll
            for (int nt = 0; nt < 8; nt++) {
                float o = (v[nt] - mu) * inv * gm[nt] + bt[nt];
                o = o > 0.f ? o : 0.f;
                z[(size_t)row * 128 + nt * 16 + ln] = o;
            }
        }
    }
}

// ------- E8 gather (bf16 h): agg16[r] = bf16(dinv[r] * sum h16[c]*dinv[c]) -------
__global__ __launch_bounds__(256) void e8_gather(
    const int* __restrict__ row_ptr, const int* __restrict__ degs,
    const int* __restrict__ adj, const float* __restrict__ dinv,
    const unsigned short* __restrict__ h16, unsigned short* __restrict__ agg16, int N) {
    int r = blockIdx.x * 4 + (threadIdx.x >> 6);
    int lane = threadIdx.x & 63;
    if (r >= N) return;
    int start = row_ptr[N + r], cnt = degs[N + r];
    float ax = 0.f, ay = 0.f;
    for (int base = 0; base < cnt; base += 64) {
        int m = cnt - base; if (m > 64) m = 64;
        int av = (base + lane < cnt) ? adj[start + base + lane] : 0;
        int j = 0;
        for (; j + 4 <= m; j += 4) {
            int c0 = __shfl(av, j), c1 = __shfl(av, j + 1);
            int c2 = __shfl(av, j + 2), c3 = __shfl(av, j + 3);
            float v0 = dinv[c0], v1 = dinv[c1], v2 = dinv[c2], v3 = dinv[c3];
            ushort2 h0 = *(const ushort2*)&h16[(size_t)c0 * 128 + lane * 2];
            ushort2 h1 = *(const ushort2*)&h16[(size_t)c1 * 128 + lane * 2];
            ushort2 h2 = *(const ushort2*)&h16[(size_t)c2 * 128 + lane * 2];
            ushort2 h3 = *(const ushort2*)&h16[(size_t)c3 * 128 + lane * 2];
            ax += us2f(h0.x) * v0 + us2f(h1.x) * v1 + us2f(h2.x) * v2 + us2f(h3.x) * v3;
            ay += us2f(h0.y) * v0 + us2f(h1.y) * v1 + us2f(h2.y) * v2 + us2f(h3.y) * v3;
        }
        for (; j < m; j++) {
            int c = __shfl(av, j);
            float vc = dinv[c];
            ushort2 hv = *(const ushort2*)&h16[(size_t)c * 128 + lane * 2];
            ax += us2f(hv.x) * vc;
            ay += us2f(hv.y) * vc;
        }
    }
    float dr = dinv[r];
    ushort2 o; o.x = f2bf(ax * dr); o.y = f2bf(ay * dr);
    *(ushort2*)&agg16[(size_t)r * 128 + lane * 2] = o;
}

// ---------------- attention coefficients (bf16 g) ----------------
__global__ void att_kernel(const unsigned short* __restrict__ g16,
                           const float* __restrict__ att_src, const float* __restrict__ att_dst,
                           float* __restrict__ a_src, float* __restrict__ a_dst, int N) {
    int tid = blockIdx.x * 256 + threadIdx.x;
    if (tid >= N * 4) return;
    int n = tid >> 2, hd = tid & 3;
    const unsigned short* gr = &g16[(size_t)n * 128 + hd * 32];
    const float* as = att_src + hd * 32;
    const float* ad = att_dst + hd * 32;
    float s = 0.f, d = 0.f;
    for (int c = 0; c < 32; c += 4) {
        ushort4 gv4 = *(const ushort4*)&gr[c];
        float g0 = us2f(gv4.x), g1 = us2f(gv4.y), g2 = us2f(gv4.z), g3 = us2f(gv4.w);
        float4 sv = *(const float4*)&as[c];
        float4 dv = *(const float4*)&ad[c];
        s += g0 * sv.x + g1 * sv.y + g2 * sv.z + g3 * sv.w;
        d += g0 * dv.x + g1 * dv.y + g2 * dv.z + g3 * dv.w;
    }
    a_src[tid] = s;
    a_dst[tid] = d;
}

// ------- GAT fused: online softmax over dst-CSR (+implicit self-loop), bf16 -------
__global__ __launch_bounds__(256) void gat_gather(
    const int* __restrict__ row_ptr, const int* __restrict__ degs,
    const int* __restrict__ adj, const float* __restrict__ a_src,
    const float* __restrict__ a_dst, const unsigned short* __restrict__ g16,
    unsigned short* __restrict__ xg16, int N) {
    int d = blockIdx.x * 4 + (threadIdx.x >> 6);
    int lane = threadIdx.x & 63;
    if (d >= N) return;
    int hd = lane >> 4;
    float ad = a_dst[d * 4 + hd];

    float e = a_src[d * 4 + hd] + ad; e = e > 0.f ? e : 0.2f * e;
    float m0 = e, l = 1.f;
    ushort2 gv0 = *(const ushort2*)&g16[(size_t)d * 128 + lane * 2];
    float accx = us2f(gv0.x), accy = us2f(gv0.y);

    int start = row_ptr[d], cnt = degs[d];
    for (int base = 0; base < cnt; base += 64) {
        int mm = cnt - base; if (mm > 64) mm = 64;
        int av = (base + lane < cnt) ? adj[start + base + lane] : 0;
        int j = 0;
        for (; j + 2 <= mm; j += 2) {
            int s0 = __shfl(av, j), s1 = __shfl(av, j + 1);
            float t0 = a_src[s0 * 4 + hd] + ad; t0 = t0 > 0.f ? t0 : 0.2f * t0;
            float t1 = a_src[s1 * 4 + hd] + ad; t1 = t1 > 0.f ? t1 : 0.2f * t1;
            ushort2 gu0 = *(const ushort2*)&g16[(size_t)s0 * 128 + lane * 2];
            ushort2 gu1 = *(const ushort2*)&g16[(size_t)s1 * 128 + lane * 2];
            float mn = fmaxf(m0, fmaxf(t0, t1));
            float sc = __expf(m0 - mn), w0 = __expf(t0 - mn), w1 = __expf(t1 - mn);
            accx = accx * sc + w0 * us2f(gu0.x) + w1 * us2f(gu1.x);
            accy = accy * sc + w0 * us2f(gu0.y) + w1 * us2f(gu1.y);
            l = l * sc + w0 + w1;
            m0 = mn;
        }
        for (; j < mm; j++) {
            int s = __shfl(av, j);
            float t0 = a_src[s * 4 + hd] + ad; t0 = t0 > 0.f ? t0 : 0.2f * t0;
            ushort2 gu = *(const ushort2*)&g16[(size_t)s * 128 + lane * 2];
            float mn = fmaxf(m0, t0);
            float sc = __expf(m0 - mn), w = __expf(t0 - mn);
            accx = accx * sc + w * us2f(gu.x);
            accy = accy * sc + w * us2f(gu.y);
            l = l * sc + w;
            m0 = mn;
        }
    }
    float inv = 1.f / l;
    ushort2 o; o.x = f2bf(accx * inv); o.y = f2bf(accy * inv);
    *(ushort2*)&xg16[(size_t)d * 128 + lane * 2] = o;
}

// --------- readout: r = relu(z@W1^T+b1); out = sigmoid(r@W2+b2) — LDS GEMM ---------
__global__ __launch_bounds__(256) void readout_kernel(
    const float* __restrict__ z, const float* __restrict__ W1, const float* __restrict__ b1,
    const float* __restrict__ W2, const float* __restrict__ b2,
    float* __restrict__ out, int N) {
    __shared__ float zs[32 * 132];
    __shared__ float wlds[64 * 132];
    __shared__ float w2s[64];
    __shared__ float b1s[64];
    const int t = threadIdx.x;
    const int row0 = blockIdx.x * 32;

    for (int i = 0; i < 4; i++) {
        int idx = i * 256 + t;
        int r = idx >> 5, c4 = idx & 31;
        float4 v = make_float4(0.f, 0.f, 0.f, 0.f);
        if (row0 + r < N) v = *(const float4*)&z[(size_t)(row0 + r) * 128 + c4 * 4];
        *(float4*)&zs[r * 132 + c4 * 4] = v;
    }
    for (int i = 0; i < 8; i++) {
        int idx = i * 256 + t;
        int o = idx >> 5, c4 = idx & 31;
        *(float4*)&wlds[o * 132 + c4 * 4] = *(const float4*)&W1[o * 128 + c4 * 4];
    }
    if (t < 64) { w2s[t] = W2[t]; b1s[t] = b1[t]; }
    __syncthreads();

    const int rg = t >> 4;
    const int cg = t & 15;
    float acc[2][4] = {};
    const float* z0 = &zs[(rg * 2) * 132];
    const float* z1 = z0 + 132;
    for (int k4 = 0; k4 < 32; k4++) {
        float4 a0 = *(const float4*)&z0[k4 * 4];
        float4 a1 = *(const float4*)&z1[k4 * 4];
#pragma unroll
        for (int j = 0; j < 4; j++) {
            float4 wv = *(const float4*)&wlds[(cg * 4 + j) * 132 + k4 * 4];
            acc[0][j] += a0.x * wv.x + a0.y * wv.y + a0.z * wv.z + a0.w * wv.w;
            acc[1][j] += a1.x * wv.x + a1.y * wv.y + a1.z * wv.z + a1.w * wv.w;
        }
    }
    float p0 = 0.f, p1 = 0.f;
#pragma unroll
    for (int j = 0; j < 4; j++) {
        int o = cg * 4 + j;
        float r0 = acc[0][j] + b1s[o]; r0 = r0 > 0.f ? r0 : 0.f;
        float r1 = acc[1][j] + b1s[o]; r1 = r1 > 0.f ? r1 : 0.f;
        p0 += r0 * w2s[o]; p1 += r1 * w2s[o];
    }
    for (int off = 8; off > 0; off >>= 1) {
        p0 += __shfl_down(p0, off, 16);
        p1 += __shfl_down(p1, off, 16);
    }
    if (cg == 0) {
        float bb = b2[0];
        int r0i = row0 + rg * 2, r1i = r0i + 1;
        if (r0i < N) out[r0i] = 1.f / (1.f + __expf(-(p0 + bb)));
        if (r1i < N) out[r1i] = 1.f / (1.f + __expf(-(p1 + bb)));
    }
}

extern "C" void kernel_launch(void* const* d_in, const int* in_sizes, int n_in,
                              void* d_out, int out_size, void* d_ws, size_t ws_size,
                              hipStream_t stream) {
    const float* x     = (const float*)d_in[0];
    const int*   ei    = (const int*)d_in[1];
    const float* W_emb = (const float*)d_in[2];
    const float* b_emb = (const float*)d_in[3];
    const float* W_e8  = (const float*)d_in[4];
    const float* W_gat = (const float*)d_in[5];
    const float* att_s = (const float*)d_in[6];
    const float* att_d = (const float*)d_in[7];
    const float* b_gat = (const float*)d_in[8];
    const float* W_fus = (const float*)d_in[9];
    const float* b_fus = (const float*)d_in[10];
    const float* gamma = (const float*)d_in[11];
    const float* beta  = (const float*)d_in[12];
    const float* W_r1  = (const float*)d_in[13];
    const float* b_r1  = (const float*)d_in[14];
    const float* W_r2  = (const float*)d_in[15];
    const float* b_r2  = (const float*)d_in[16];

    const int N = in_sizes[0] / 128;
    const int E = in_sizes[1] / 2;
    const int* rowp = ei;
    const int* colp = ei + E;
    const int total = 2 * N;
    const int P = (total + SCAN_TILE - 1) / SCAN_TILE;
    const int win = (total + NWIN - 1) / NWIN;
    const int GB = (N + 127) / 128;   // MFMA GEMM grid

    const size_t NF = (size_t)N * 128;
    char* base = (char*)d_ws;
    float* B_h             = (float*)base;                       // fp32 h (residual)
    unsigned short* h16    = (unsigned short*)(base + NF * 4);
    unsigned short* bufA   = h16 + NF;        // agg16, then xg16
    unsigned short* xe816  = bufA + NF;
    unsigned short* g16    = xe816 + NF;
    float* B_z             = (float*)(g16 + NF);                 // fp32 z
    float* dinv  = B_z + NF;
    float* a_src = dinv + N;
    float* a_dst = a_src + (size_t)4 * N;
    float* bfus2 = a_dst + (size_t)4 * N;
    unsigned short* W16a = (unsigned short*)(bfus2 + 128);
    unsigned short* We16 = W16a;
    unsigned short* W816 = W16a + 16384;
    unsigned short* Wg16 = W16a + 32768;
    unsigned short* Wf16 = W16a + 49152;
    int* degs    = (int*)(W16a + 81920);
    int* row_ptr = degs + total;
    int* cursor  = row_ptr + total;
    int* part    = cursor + total;
    int* adj     = part + 1024;       // 2E ints

    // --- prep + weight convert + CSR build ---
    prep_kernel<<<1, 128, 0, stream>>>(b_gat, W_fus, b_fus, bfus2);
    convert_w<<<320, 256, 0, stream>>>(W_emb, W_e8, W_gat, W_fus, W16a);
    hipMemsetAsync(degs, 0, (size_t)total * 4, stream);
    count_kernel<<<(E + 255) / 256, 256, 0, stream>>>(rowp, colp, degs, E, N);
    scan_reduce<<<P, 256, 0, stream>>>(degs, part, total);
    scan_partials<<<1, 64, 0, stream>>>(part, P);
    scan_write<<<P, 256, 0, stream>>>(degs, part, row_ptr, cursor, dinv, total, N);
    fill_win<<<NWIN * NCHUNK, 256, 0, stream>>>(rowp, colp, cursor, adj, E, N, win);

    // --- h = x @ W_emb^T + b_emb  (fp32 + bf16 outputs, fp32 A converted inline) ---
    gemm_mfma<true, true, true, true><<<GB, 256, 0, stream>>>(x, We16, b_emb, B_h, h16, N);

    // --- E8: gather (bf16) + linear (MFMA) ---
    e8_gather<<<(N + 3) / 4, 256, 0, stream>>>(row_ptr, degs, adj, dinv, h16, bufA, N);
    gemm_mfma<false, false, false, true><<<GB, 256, 0, stream>>>(bufA, W816, nullptr,
                                                                 nullptr, xe816, N);

    // --- GAT: g (MFMA, bf16 out) + att + fused online-softmax gather ---
    gemm_mfma<false, false, false, true><<<GB, 256, 0, stream>>>(h16, Wg16, nullptr,
                                                                 nullptr, g16, N);
    att_kernel<<<(4 * N + 255) / 256, 256, 0, stream>>>(g16, att_s, att_d, a_src, a_dst, N);
    gat_gather<<<(N + 3) / 4, 256, 0, stream>>>(row_ptr, degs, adj, a_src, a_dst, g16,
                                                bufA, N);

    // --- fused fusion (MFMA K=256) + residual + LayerNorm + ReLU -> z ---
    fusion_ln_mfma<<<GB, 256, 0, stream>>>(xe816, bufA, Wf16, bfus2, B_h,
                                           gamma, beta, B_z, N);

    // --- readout ---
    readout_kernel<<<(N + 31) / 32, 256, 0, stream>>>(B_z, W_r1, b_r1, W_r2, b_r2,
                                                      (float*)d_out, N);
}